// Round 18
// baseline (100.014 us; speedup 1.0000x reference)
//
#include <hip/hip_runtime.h>

#define EPS 1e-6f

__device__ __forceinline__ float elu1(float x) {
    // elu(x) + 1  ==  x > 0 ? x + 1 : exp(x)
    return x > 0.f ? x + 1.f : __expf(x);
}

__device__ __forceinline__ float fidx(const float4& v, int i) {
    return i == 0 ? v.x : i == 1 ? v.y : i == 2 ? v.z : v.w;  // i compile-time
}

#define LGKMCNT0() asm volatile("s_waitcnt lgkmcnt(0)" ::: "memory")
// raw barrier: does NOT drain vmcnt, so global loads stay in flight.
#define BAR() do { LGKMCNT0(); __builtin_amdgcn_s_barrier(); \
                   asm volatile("" ::: "memory"); } while (0)

// ---------------------------------------------------------------------------
// Phase 1 (R18): NO MFMA/AGPR. Evidence: R15's probe (same skeleton, no
// MFMA path) ran at the memory floor (~19us full-scale); every MFMA variant
// (R5-R17, 8 different structures) pinned at 55-70us; out_kernel — fp32-FMA,
// computationally isomorphic to this kernel — runs at floor. So: R13's
// probe-validated staging skeleton + R1's verified fp32 compute mapping.
// Thread tile (R1, natural layouts, zero transpose): m0=(t>>4)*4,
// d0=(t&15)*4; per s: vv=float4 Vls[s][m0] (16-lane broadcast),
// kk=float4 Kls[s][d0] (2-way bank = free), 16 FMAs -> acc[4][4].
// No cross-wave combine: each thread owns 16 distinct (m,d) outputs ->
// straight coalesced dump pb[(i*4+j)*256+t] (1KB per store instr).
// ksum: R13's proven staging-side accumulate + LDS reduce.
// ---------------------------------------------------------------------------
template<int ITERS>
__global__ __launch_bounds__(256, 2) void kv_partial_kernel(
    const float* __restrict__ keys, const float* __restrict__ values,
    const float* __restrict__ mask, float* __restrict__ pkv,
    float* __restrict__ pks)
{
    __shared__ float Kls[64][68];    // 17.4 KB
    __shared__ float Vls[64][68];    // 17.4 KB
    __shared__ float Mls[ITERS * 64];

    const int nh = blockIdx.x, n = nh >> 4, h = nh & 15;
    const int chunk = blockIdx.y;
    const int t = threadIdx.x;
    const int r0 = t >> 4, c4 = (t & 15) * 4;   // staging role
    const int m0 = (t >> 4) * 4, d0 = (t & 15) * 4;  // compute role (R1)

    const int s0 = chunk * (ITERS * 64);
    const float* kb = keys   + ((size_t)(n * 4096 + s0) * 16 + h) * 64;
    const float* vb = values + ((size_t)(n * 4096 + s0) * 16 + h) * 64;

    if (t < ITERS * 16)
        *(float4*)&Mls[t * 4] = *(const float4*)(mask + n * 4096 + s0 + t * 4);

    float acc[4][4];
    #pragma unroll
    for (int i = 0; i < 4; ++i)
        #pragma unroll
        for (int j = 0; j < 4; ++j) acc[i][j] = 0.f;
    float4 ks4 = make_float4(0.f, 0.f, 0.f, 0.f);

    float4 kr[4], vr[4];
    #pragma unroll
    for (int k = 0; k < 4; ++k) {     // prologue: tile 0 (8 float4/thread)
        const size_t go = (size_t)(r0 + 16 * k) * 1024 + c4;
        kr[k] = *(const float4*)(kb + go);
        vr[k] = *(const float4*)(vb + go);
    }

    #pragma unroll
    for (int it = 0; it < ITERS; ++it) {
        BAR();   // (A) prior tile's compute reads done; Mls visible at it==0
        #pragma unroll
        for (int k = 0; k < 4; ++k) {
            const float msk = Mls[it * 64 + r0 + 16 * k];
            float4 kk = kr[k];
            kk.x = elu1(kk.x) * msk; kk.y = elu1(kk.y) * msk;
            kk.z = elu1(kk.z) * msk; kk.w = elu1(kk.w) * msk;
            ks4.x += kk.x; ks4.y += kk.y; ks4.z += kk.z; ks4.w += kk.w;
            *(float4*)&Kls[r0 + 16 * k][c4] = kk;
            *(float4*)&Vls[r0 + 16 * k][c4] = vr[k];
        }
        BAR();   // (B) tile staged & visible
        if (it + 1 < ITERS) {          // issue next tile; stays in flight
            #pragma unroll
            for (int k = 0; k < 4; ++k) {
                const size_t go = (size_t)(r0 + 16 * k + 64 * (it + 1)) * 1024 + c4;
                kr[k] = *(const float4*)(kb + go);
                vr[k] = *(const float4*)(vb + go);
            }
        }
        // compute: per s, 2x float4 LDS reads -> 16 FMA (R1 mapping)
        #pragma unroll 4
        for (int s = 0; s < 64; ++s) {
            const float4 vv = *(const float4*)&Vls[s][m0];
            const float4 kk = *(const float4*)&Kls[s][d0];
            #pragma unroll
            for (int i = 0; i < 4; ++i) {
                const float vi = fidx(vv, i);
                acc[i][0] = fmaf(vi, kk.x, acc[i][0]);
                acc[i][1] = fmaf(vi, kk.y, acc[i][1]);
                acc[i][2] = fmaf(vi, kk.z, acc[i][2]);
                acc[i][3] = fmaf(vi, kk.w, acc[i][3]);
            }
        }
    }

    // ---- ksum block reduce (thread covered cols c4..c4+3 of its rows)
    BAR();   // last tile's compute reads done -> Kls reusable
    *(float4*)&Kls[r0][c4] = ks4;
    BAR();
    if (t < 64) {
        float s = 0.f;
        #pragma unroll
        for (int r = 0; r < 16; ++r) s += Kls[r][t];
        pks[((size_t)chunk * 64 + nh) * 64 + t] = s;
    }

    // ---- dump: thread owns (m = m0+i, d = d0+j); slot k=i*4+j
    float* pb = pkv + ((size_t)chunk * 64 + nh) * 4096;
    #pragma unroll
    for (int i = 0; i < 4; ++i)
        #pragma unroll
        for (int j = 0; j < 4; ++j)
            pb[(i * 4 + j) * 256 + t] = acc[i][j];
}

// ---------------------------------------------------------------------------
// Reduce + unscramble: kvt[nh][d][m] = sum_c pkv[c][nh][k][t] where
// m=(t>>4)*4+(k>>2), d=(t&15)*4+(k&3).  ksum[nh][d] = sum_c pks.
// ---------------------------------------------------------------------------
__global__ __launch_bounds__(256) void kv_reduce_kernel(
    const float* __restrict__ pkv, const float* __restrict__ pks,
    float* __restrict__ kvt, float* __restrict__ ksum, int CH)
{
    const int nh = blockIdx.x;
    const int f4 = blockIdx.y * 256 + threadIdx.x;   // float4 slot 0..1023
    float4 s4 = make_float4(0.f, 0.f, 0.f, 0.f);
    #pragma unroll 4
    for (int c = 0; c < CH; ++c) {
        const float4 v = *(const float4*)(pkv + ((size_t)c * 64 + nh) * 4096 + f4 * 4);
        s4.x += v.x; s4.y += v.y; s4.z += v.z; s4.w += v.w;
    }
    const float vals[4] = {s4.x, s4.y, s4.z, s4.w};
    const int k = f4 >> 6;            // const over this slot's 4 floats
    const int tb = (f4 & 63) * 4;
    #pragma unroll
    for (int u = 0; u < 4; ++u) {
        const int t = tb + u;
        const int m = ((t >> 4) << 2) + (k >> 2);
        const int d = ((t & 15) << 2) + (k & 3);
        kvt[(size_t)nh * 4096 + d * 64 + m] = vals[u];
    }

    if (blockIdx.y == 0 && threadIdx.x < 64) {
        float s = 0.f;
        #pragma unroll 4
        for (int c = 0; c < CH; ++c)
            s += pks[((size_t)c * 64 + nh) * 64 + threadIdx.x];
        ksum[nh * 64 + threadIdx.x] = s;
    }
}

// ---------------------------------------------------------------------------
// Phase 2: out[n,l,h,m] = z_l * sum_d Q'[l,d] * KVT[d,m],
//          z_l = 1/(sum_d Q'[l,d]*Ksum[d] + EPS)   (R8 version, ~floor)
// ---------------------------------------------------------------------------
__global__ __launch_bounds__(256) void out_kernel(
    const float* __restrict__ queries, const float* __restrict__ kvt,
    const float* __restrict__ ksum, float* __restrict__ out)
{
    __shared__ float Qs[64][68];    // [l][d]
    __shared__ float KVs[64][68];   // [d][m]
    __shared__ float Ksm[64];

    const int nh = blockIdx.x;
    const int n = nh >> 4, h = nh & 15;
    const int t = threadIdx.x;
    const int l0 = blockIdx.y * 64;

    #pragma unroll
    for (int k = 0; k < 4; ++k) {
        const int idx = t + k * 256;
        *(float4*)&KVs[idx >> 4][(idx & 15) * 4] =
            *(const float4*)(kvt + (size_t)nh * 4096 + idx * 4);
    }
    if (t < 64) Ksm[t] = ksum[nh * 64 + t];

    #pragma unroll
    for (int k = 0; k < 4; ++k) {
        const int idx = t + k * 256;
        const int row = idx >> 4, seg = idx & 15;
        const size_t g = ((size_t)(n * 4096 + l0 + row) * 16 + h) * 64 + seg * 4;
        float4 q4 = *(const float4*)(queries + g);
        q4.x = elu1(q4.x);
        q4.y = elu1(q4.y);
        q4.z = elu1(q4.z);
        q4.w = elu1(q4.w);
        *(float4*)&Qs[row][seg * 4] = q4;
    }
    __syncthreads();

    const int mg = t & 7;          // m cols 4mg..+3 and 32+4mg..+3
    const int lg = t >> 3;         // 0..31; rows lg, lg+32

    float acc[2][8];
    float zacc[2] = {0.f, 0.f};
    #pragma unroll
    for (int i = 0; i < 2; ++i)
        #pragma unroll
        for (int j = 0; j < 8; ++j) acc[i][j] = 0.f;

    #pragma unroll 4
    for (int d0 = 0; d0 < 64; d0 += 4) {
        const float4 km4 = *(const float4*)&Ksm[d0];
        float4 q[2];
        q[0] = *(const float4*)&Qs[lg][d0];
        q[1] = *(const float4*)&Qs[lg + 32][d0];
        #pragma unroll
        for (int i = 0; i < 2; ++i)
            zacc[i] += q[i].x * km4.x + q[i].y * km4.y +
                       q[i].z * km4.z + q[i].w * km4.w;
        #pragma unroll
        for (int r = 0; r < 4; ++r) {
            const float4 kva = *(const float4*)&KVs[d0 + r][mg * 4];
            const float4 kvb = *(const float4*)&KVs[d0 + r][32 + mg * 4];
            #pragma unroll
            for (int i = 0; i < 2; ++i) {
                const float qc = fidx(q[i], r);
                acc[i][0] = fmaf(qc, kva.x, acc[i][0]);
                acc[i][1] = fmaf(qc, kva.y, acc[i][1]);
                acc[i][2] = fmaf(qc, kva.z, acc[i][2]);
                acc[i][3] = fmaf(qc, kva.w, acc[i][3]);
                acc[i][4] = fmaf(qc, kvb.x, acc[i][4]);
                acc[i][5] = fmaf(qc, kvb.y, acc[i][5]);
                acc[i][6] = fmaf(qc, kvb.z, acc[i][6]);
                acc[i][7] = fmaf(qc, kvb.w, acc[i][7]);
            }
        }
    }

    #pragma unroll
    for (int i = 0; i < 2; ++i) {
        const float z = 1.f / (zacc[i] + EPS);
        const int row = l0 + lg + 32 * i;
        const size_t g = ((size_t)(n * 4096 + row) * 16 + h) * 64;
        float4 o;
        o.x = acc[i][0] * z; o.y = acc[i][1] * z;
        o.z = acc[i][2] * z; o.w = acc[i][3] * z;
        *(float4*)(out + g + mg * 4) = o;
        o.x = acc[i][4] * z; o.y = acc[i][5] * z;
        o.z = acc[i][6] * z; o.w = acc[i][7] * z;
        *(float4*)(out + g + 32 + mg * 4) = o;
    }
}

extern "C" void kernel_launch(void* const* d_in, const int* in_sizes, int n_in,
                              void* d_out, int out_size, void* d_ws, size_t ws_size,
                              hipStream_t stream) {
    const float* queries = (const float*)d_in[0];
    const float* keys    = (const float*)d_in[1];
    const float* values  = (const float*)d_in[2];
    const float* mask    = (const float*)d_in[3];
    float* out = (float*)d_out;

    const int CH = 16;   // 18MB workspace (proven fits in R1)

    float* pkv  = (float*)d_ws;                      // [16][64][4096] (k,t)
    float* pks  = pkv + (size_t)CH * 64 * 4096;      // [16][64][64]
    float* kvt  = pks + (size_t)CH * 64 * 64;        // [64][4096] (d,m)
    float* ksum = kvt + (size_t)64 * 4096;           // [64][64]

    kv_partial_kernel<4><<<dim3(64, CH), 256, 0, stream>>>(keys, values, mask,
                                                           pkv, pks);
    kv_reduce_kernel<<<dim3(64, 4), 256, 0, stream>>>(pkv, pks, kvt, ksum, CH);
    out_kernel<<<dim3(64, 64), 256, 0, stream>>>(queries, kvt, ksum, out);
}

// Round 19
// 99.343 us; speedup vs baseline: 1.0068x; 1.0068x over previous
//
#include <hip/hip_runtime.h>

#define EPS 1e-6f

__device__ __forceinline__ float elu1(float x) {
    // elu(x) + 1  ==  x > 0 ? x + 1 : exp(x)
    return x > 0.f ? x + 1.f : __expf(x);
}

__device__ __forceinline__ float fidx(const float4& v, int i) {
    return i == 0 ? v.x : i == 1 ? v.y : i == 2 ? v.z : v.w;  // i compile-time
}

#define LGKMCNT0() asm volatile("s_waitcnt lgkmcnt(0)" ::: "memory")
// raw barrier: does NOT drain vmcnt, so global loads stay in flight.
#define BAR() do { LGKMCNT0(); __builtin_amdgcn_s_barrier(); \
                   asm volatile("" ::: "memory"); } while (0)

// ---------------------------------------------------------------------------
// Phase 1 (R19): LDS-INSTRUCTION-THROUGHPUT fix. R18 closed the books:
// 4x4 tile = 2 ds_read_b128 per 16 FMA -> 1.07G FMA x (2/16) x 12cyc/CU
// = ~41us LDS-pipe + ~19us staging skeleton (R15 probe) = the 60us wall.
// Now: per-thread 8m x 8d (64 acc), one wave covers the whole 64x64 output
// (lanes in 8x8 grid), so the 4 waves split the tile's s-range 4-ways and
// tree-combine at the end (R13-proven combine, buffers overlay Kls/Vls).
// Per s-step: 4 b128 reads per 64 FMA (1 B/FMA) -> LDS-pipe ~20us.
// Staging skeleton/BAR pipeline/ksum identical to R18 (passing).
// XCD swizzle: heads sharing 4KB lines -> same XCD L2 (bijective remap).
// ---------------------------------------------------------------------------
template<int ITERS>
__global__ __launch_bounds__(256, 2) void kv_partial_kernel(
    const float* __restrict__ keys, const float* __restrict__ values,
    const float* __restrict__ mask, float* __restrict__ pkv,
    float* __restrict__ pks)
{
    __shared__ float Kls[64][68];    // 17.4 KB; combine buf 0 overlay
    __shared__ float Vls[64][68];    // 17.4 KB; combine buf 1 overlay
    __shared__ float Mls[ITERS * 64];

    // bijective XCD swizzle: all 16 heads of (n,chunk) share b%8 -> same XCD
    const int b = blockIdx.x + 64 * blockIdx.y;   // 0..64*CH-1 (CH=16)
    const int xr = b & 7, q = b >> 3;             // q 0..127
    const int h = q & 15, g = q >> 4;             // g 0..7
    const int pair = xr + 8 * g;                  // 0..63
    const int n = pair & 3, chunk = pair >> 2;    // chunk 0..15
    const int nh = n * 16 + h;

    const int t = threadIdx.x, wv = t >> 6, l = t & 63;
    const int r0 = t >> 4, c4 = (t & 15) * 4;        // staging role
    const int m0 = (l & 7) * 8, d0 = (l >> 3) * 8;   // compute role (8x8)

    const int s0 = chunk * (ITERS * 64);
    const float* kb = keys   + ((size_t)(n * 4096 + s0) * 16 + h) * 64;
    const float* vb = values + ((size_t)(n * 4096 + s0) * 16 + h) * 64;

    if (t < ITERS * 16)
        *(float4*)&Mls[t * 4] = *(const float4*)(mask + n * 4096 + s0 + t * 4);

    float acc[8][8];
    #pragma unroll
    for (int i = 0; i < 8; ++i)
        #pragma unroll
        for (int j = 0; j < 8; ++j) acc[i][j] = 0.f;
    float4 ks4 = make_float4(0.f, 0.f, 0.f, 0.f);

    float4 kr[4], vr[4];
    #pragma unroll
    for (int k = 0; k < 4; ++k) {     // prologue: tile 0 (8 float4/thread)
        const size_t go = (size_t)(r0 + 16 * k) * 1024 + c4;
        kr[k] = *(const float4*)(kb + go);
        vr[k] = *(const float4*)(vb + go);
    }

    #pragma unroll
    for (int it = 0; it < ITERS; ++it) {
        BAR();   // (A) prior tile's compute reads done; Mls visible at it==0
        #pragma unroll
        for (int k = 0; k < 4; ++k) {
            const float msk = Mls[it * 64 + r0 + 16 * k];
            float4 kk = kr[k];
            kk.x = elu1(kk.x) * msk; kk.y = elu1(kk.y) * msk;
            kk.z = elu1(kk.z) * msk; kk.w = elu1(kk.w) * msk;
            ks4.x += kk.x; ks4.y += kk.y; ks4.z += kk.z; ks4.w += kk.w;
            *(float4*)&Kls[r0 + 16 * k][c4] = kk;
            *(float4*)&Vls[r0 + 16 * k][c4] = vr[k];
        }
        BAR();   // (B) tile staged & visible
        if (it + 1 < ITERS) {          // issue next tile; stays in flight
            #pragma unroll
            for (int k = 0; k < 4; ++k) {
                const size_t go = (size_t)(r0 + 16 * k + 64 * (it + 1)) * 1024 + c4;
                kr[k] = *(const float4*)(kb + go);
                vr[k] = *(const float4*)(vb + go);
            }
        }
        // compute: wave wv handles s in [16wv, 16wv+16); per s:
        // 4x ds_read_b128 -> 64 FMA (1 B/FMA; was 2 B/FMA = the wall)
        #pragma unroll 2
        for (int s16 = 0; s16 < 16; ++s16) {
            const int s = 16 * wv + s16;
            const float4 va = *(const float4*)&Vls[s][m0];
            const float4 vc = *(const float4*)&Vls[s][m0 + 4];
            const float4 ka = *(const float4*)&Kls[s][d0];
            const float4 kc = *(const float4*)&Kls[s][d0 + 4];
            const float vv[8] = {va.x, va.y, va.z, va.w, vc.x, vc.y, vc.z, vc.w};
            const float kk[8] = {ka.x, ka.y, ka.z, ka.w, kc.x, kc.y, kc.z, kc.w};
            #pragma unroll
            for (int i = 0; i < 8; ++i)
                #pragma unroll
                for (int j = 0; j < 8; ++j)
                    acc[i][j] = fmaf(vv[i], kk[j], acc[i][j]);
        }
    }

    // ---- ksum block reduce (thread covered cols c4..c4+3 of its rows)
    BAR();   // last tile's compute reads done -> Kls reusable
    *(float4*)&Kls[r0][c4] = ks4;
    BAR();
    if (t < 64) {
        float s = 0.f;
        #pragma unroll
        for (int r = 0; r < 16; ++r) s += Kls[r][t];
        pks[((size_t)chunk * 64 + nh) * 64 + t] = s;
    }
    BAR();

    // ---- acc tree-combine across waves (flat overlays; [k][l] layout)
    float* cb0 = &Kls[0][0];
    float* cb1 = &Vls[0][0];
#define FLATW(BUF)                                                         \
    { _Pragma("unroll") for (int i = 0; i < 8; ++i)                        \
      _Pragma("unroll") for (int j = 0; j < 8; ++j)                        \
          BUF[(i * 8 + j) * 64 + l] = acc[i][j]; }
#define FLATR(BUF)                                                         \
    { _Pragma("unroll") for (int i = 0; i < 8; ++i)                        \
      _Pragma("unroll") for (int j = 0; j < 8; ++j)                        \
          acc[i][j] += BUF[(i * 8 + j) * 64 + l]; }
    if (wv == 2) FLATW(cb0);
    if (wv == 3) FLATW(cb1);
    BAR();
    if (wv == 0) FLATR(cb0);
    if (wv == 1) FLATR(cb1);
    BAR();
    if (wv == 1) FLATW(cb0);
    BAR();
    if (wv == 0) {
        FLATR(cb0);
        // dump scrambled [k][l] (fully coalesced; reduce unscrambles)
        float* pb = pkv + ((size_t)chunk * 64 + nh) * 4096;
        #pragma unroll
        for (int i = 0; i < 8; ++i)
            #pragma unroll
            for (int j = 0; j < 8; ++j)
                pb[(i * 8 + j) * 64 + l] = acc[i][j];
    }
#undef FLATW
#undef FLATR
}

// ---------------------------------------------------------------------------
// Reduce + unscramble: slot k*64+l holds (m = (l&7)*8 + (k>>3),
// d = (l>>3)*8 + (k&7)).  kvt[nh][d][m] = sum_c;  ksum[nh][d] = sum_c pks.
// ---------------------------------------------------------------------------
__global__ __launch_bounds__(256) void kv_reduce_kernel(
    const float* __restrict__ pkv, const float* __restrict__ pks,
    float* __restrict__ kvt, float* __restrict__ ksum, int CH)
{
    const int nh = blockIdx.x;
    const int f4 = blockIdx.y * 256 + threadIdx.x;   // float4 slot 0..1023
    float4 s4 = make_float4(0.f, 0.f, 0.f, 0.f);
    #pragma unroll 4
    for (int c = 0; c < CH; ++c) {
        const float4 v = *(const float4*)(pkv + ((size_t)c * 64 + nh) * 4096 + f4 * 4);
        s4.x += v.x; s4.y += v.y; s4.z += v.z; s4.w += v.w;
    }
    const float vals[4] = {s4.x, s4.y, s4.z, s4.w};
    const int k = f4 >> 4;            // const over this slot's 4 floats
    const int lb = (f4 & 15) * 4;
    #pragma unroll
    for (int u = 0; u < 4; ++u) {
        const int l = lb + u;
        const int m = ((l & 7) << 3) + (k >> 3);
        const int d = ((l >> 3) << 3) + (k & 7);
        kvt[(size_t)nh * 4096 + d * 64 + m] = vals[u];
    }

    if (blockIdx.y == 0 && threadIdx.x < 64) {
        float s = 0.f;
        #pragma unroll 4
        for (int c = 0; c < CH; ++c)
            s += pks[((size_t)c * 64 + nh) * 64 + threadIdx.x];
        ksum[nh * 64 + threadIdx.x] = s;
    }
}

// ---------------------------------------------------------------------------
// Phase 2: out[n,l,h,m] = z_l * sum_d Q'[l,d] * KVT[d,m],
//          z_l = 1/(sum_d Q'[l,d]*Ksum[d] + EPS)
// R8 structure + XCD swizzle (heads of one n share Q cache lines).
// ---------------------------------------------------------------------------
__global__ __launch_bounds__(256) void out_kernel(
    const float* __restrict__ queries, const float* __restrict__ kvt,
    const float* __restrict__ ksum, float* __restrict__ out)
{
    __shared__ float Qs[64][68];    // [l][d]
    __shared__ float KVs[64][68];   // [d][m]
    __shared__ float Ksm[64];

    // bijective XCD swizzle: 16 heads of (n,lchunk) share b%8
    const int b = blockIdx.x + 64 * blockIdx.y;   // 0..4095
    const int xr = b & 7, q0 = b >> 3;            // q0 0..511
    const int h = q0 & 15, g = q0 >> 4;           // g 0..31
    const int u0 = xr + 8 * g;                    // 0..255
    const int n = u0 & 3, lchunk = u0 >> 2;       // lchunk 0..63
    const int nh = n * 16 + h;
    const int l0 = lchunk * 64;

    const int t = threadIdx.x;

    #pragma unroll
    for (int k = 0; k < 4; ++k) {
        const int idx = t + k * 256;
        *(float4*)&KVs[idx >> 4][(idx & 15) * 4] =
            *(const float4*)(kvt + (size_t)nh * 4096 + idx * 4);
    }
    if (t < 64) Ksm[t] = ksum[nh * 64 + t];

    #pragma unroll
    for (int k = 0; k < 4; ++k) {
        const int idx = t + k * 256;
        const int row = idx >> 4, seg = idx & 15;
        const size_t g2 = ((size_t)(n * 4096 + l0 + row) * 16 + h) * 64 + seg * 4;
        float4 q4 = *(const float4*)(queries + g2);
        q4.x = elu1(q4.x);
        q4.y = elu1(q4.y);
        q4.z = elu1(q4.z);
        q4.w = elu1(q4.w);
        *(float4*)&Qs[row][seg * 4] = q4;
    }
    __syncthreads();

    const int mg = t & 7;          // m cols 4mg..+3 and 32+4mg..+3
    const int lg = t >> 3;         // 0..31; rows lg, lg+32

    float acc[2][8];
    float zacc[2] = {0.f, 0.f};
    #pragma unroll
    for (int i = 0; i < 2; ++i)
        #pragma unroll
        for (int j = 0; j < 8; ++j) acc[i][j] = 0.f;

    #pragma unroll 4
    for (int d0 = 0; d0 < 64; d0 += 4) {
        const float4 km4 = *(const float4*)&Ksm[d0];
        float4 q[2];
        q[0] = *(const float4*)&Qs[lg][d0];
        q[1] = *(const float4*)&Qs[lg + 32][d0];
        #pragma unroll
        for (int i = 0; i < 2; ++i)
            zacc[i] += q[i].x * km4.x + q[i].y * km4.y +
                       q[i].z * km4.z + q[i].w * km4.w;
        #pragma unroll
        for (int r = 0; r < 4; ++r) {
            const float4 kva = *(const float4*)&KVs[d0 + r][mg * 4];
            const float4 kvb = *(const float4*)&KVs[d0 + r][32 + mg * 4];
            #pragma unroll
            for (int i = 0; i < 2; ++i) {
                const float qc = fidx(q[i], r);
                acc[i][0] = fmaf(qc, kva.x, acc[i][0]);
                acc[i][1] = fmaf(qc, kva.y, acc[i][1]);
                acc[i][2] = fmaf(qc, kva.z, acc[i][2]);
                acc[i][3] = fmaf(qc, kva.w, acc[i][3]);
                acc[i][4] = fmaf(qc, kvb.x, acc[i][4]);
                acc[i][5] = fmaf(qc, kvb.y, acc[i][5]);
                acc[i][6] = fmaf(qc, kvb.z, acc[i][6]);
                acc[i][7] = fmaf(qc, kvb.w, acc[i][7]);
            }
        }
    }

    #pragma unroll
    for (int i = 0; i < 2; ++i) {
        const float z = 1.f / (zacc[i] + EPS);
        const int row = l0 + lg + 32 * i;
        const size_t g2 = ((size_t)(n * 4096 + row) * 16 + h) * 64;
        float4 o;
        o.x = acc[i][0] * z; o.y = acc[i][1] * z;
        o.z = acc[i][2] * z; o.w = acc[i][3] * z;
        *(float4*)(out + g2 + mg * 4) = o;
        o.x = acc[i][4] * z; o.y = acc[i][5] * z;
        o.z = acc[i][6] * z; o.w = acc[i][7] * z;
        *(float4*)(out + g2 + 32 + mg * 4) = o;
    }
}

extern "C" void kernel_launch(void* const* d_in, const int* in_sizes, int n_in,
                              void* d_out, int out_size, void* d_ws, size_t ws_size,
                              hipStream_t stream) {
    const float* queries = (const float*)d_in[0];
    const float* keys    = (const float*)d_in[1];
    const float* values  = (const float*)d_in[2];
    const float* mask    = (const float*)d_in[3];
    float* out = (float*)d_out;

    const int CH = 16;   // 18MB workspace (proven fits in R1)

    float* pkv  = (float*)d_ws;                      // [16][64][4096] (k,l)
    float* pks  = pkv + (size_t)CH * 64 * 4096;      // [16][64][64]
    float* kvt  = pks + (size_t)CH * 64 * 64;        // [64][4096] (d,m)
    float* ksum = kvt + (size_t)64 * 4096;           // [64][64]

    kv_partial_kernel<4><<<dim3(64, CH), 256, 0, stream>>>(keys, values, mask,
                                                           pkv, pks);
    kv_reduce_kernel<<<dim3(64, 4), 256, 0, stream>>>(pkv, pks, kvt, ksum, CH);
    out_kernel<<<dim3(64, 64), 256, 0, stream>>>(queries, kvt, ksum, out);
}